// Round 15
// baseline (20.910 us; speedup 1.0000x reference)
//
#include <hip/hip_runtime.h>
#include <math.h>

namespace {
constexpr int P = 4096, O = 32, H = 26, V = 48;
constexpr float EPSV = 1e-4f;         // strict < EPSV == numpy's (f32 <= 1e-4 f64)
}

// clang fuses fmaxf(fmaxf(a,b),c) -> v_max3_f32 (gfx9+)
__device__ __forceinline__ float max3f(float a, float b, float c) {
    return fmaxf(fmaxf(a, b), c);
}
// clang fuses to v_min3_u32
__device__ __forceinline__ unsigned min3u(unsigned a, unsigned b, unsigned c) {
    const unsigned ab = a < b ? a : b;
    return ab < c ? ab : c;
}

// One thread per (point p, object o).
// Face operands fully registerized: ax/ay/az/s[26] in VGPRs (compile-time
// indices only). t_j = s_j + nsh*(a_h . a_j) computed on the fly via 3 FMAs
// (Gram never materialized; NO sG in LDS). psq = nsh^2 * ||a_h||^2 from the
// per-h sAb read. s_j keeps the reference's exact rounding (argmax/is_neg
// exact); one sqrt per pass (correctly-rounded sqrt is monotone).
// Edge pass: packed-uint argmin via v_min3_u32, winner recomputed (bitwise).
// Face loop ROLLED (R10: full unroll -> 256 VGPR + spill).
__global__ __launch_bounds__(256) void zono_kernel(
    const float* __restrict__ point,   // [P][3]
    const float* __restrict__ hA,      // [O][H][3]
    const float* __restrict__ hb,      // [O][H]
    const float* __restrict__ v1g,     // [O][V][3]
    const float* __restrict__ v2g,     // [O][V][3]
    float* __restrict__ dist_out,      // [P][O]
    float* __restrict__ grad_out)      // [P][O][3]
{
    __shared__ float4 sAb[H];            // {a0,a1,a2,b}
    __shared__ float4 sV1[V];            // {v1_0,v1_1,v1_2, inv_den}
    __shared__ float4 sE[V];             // {e0,e1,e2, -(v1.e)*inv_den}

    const int o   = blockIdx.y;
    const int tid = threadIdx.x;

    if (tid < H) {
        const float* a = hA + (o * H + tid) * 3;
        sAb[tid] = make_float4(a[0], a[1], a[2], hb[o * H + tid]);
    } else if (tid >= 32 && tid < 32 + V) {
        const int v = tid - 32;
        const float* A1 = v1g + (o * V + v) * 3;
        const float* A2 = v2g + (o * V + v) * 3;
        const float x0 = A1[0], x1 = A1[1], x2 = A1[2];
        const float e0 = __fsub_rn(A2[0], x0);
        const float e1 = __fsub_rn(A2[1], x1);
        const float e2 = __fsub_rn(A2[2], x2);
        const float den = __fadd_rn(__fadd_rn(__fmul_rn(e0, e0), __fmul_rn(e1, e1)),
                                    __fmul_rn(e2, e2));
        const float inv = __fdiv_rn(1.f, den);
        const float cv  = __fadd_rn(__fadd_rn(__fmul_rn(x0, e0), __fmul_rn(x1, e1)),
                                    __fmul_rn(x2, e2));
        const float nci = -__fmul_rn(cv, inv);
        sV1[v] = make_float4(x0, x1, x2, inv);
        sE[v]  = make_float4(e0, e1, e2, nci);
    }
    __syncthreads();

    const int p = blockIdx.x * blockDim.x + tid;
    const float p0 = point[p * 3 + 0];
    const float p1 = point[p * 3 + 1];
    const float p2 = point[p * 3 + 2];

    // ---- register face table + s_j (exact reference rounding) + argmax ----
    float ax[H], ay[H], az[H], s[H];     // compile-time indexed only
    float maxv = -INFINITY; int maxi = 0;
    #pragma unroll
    for (int j = 0; j < H; ++j) {
        const float4 ab = sAb[j];
        ax[j] = ab.x; ay[j] = ab.y; az[j] = ab.z;
        s[j] = __fsub_rn(
            __fadd_rn(__fadd_rn(__fmul_rn(p0, ab.x), __fmul_rn(p1, ab.y)),
                      __fmul_rn(p2, ab.z)),
            ab.w);
        if (s[j] > maxv) { maxv = s[j]; maxi = j; }    // first argmax
    }
    const bool is_neg = (maxv <= 0.f);

    // ---- face pass (ROLLED h): t_j = s_j + nsh*(a_h . a_j), on-the-fly ----
    float minpsq = INFINITY; int mini = 0;
    for (int h = 0; h < H; ++h) {
        const float4 ab = sAb[h];                       // 1 broadcast LDS read
        const float dot = __fadd_rn(__fadd_rn(__fmul_rn(p0, ab.x),
                                              __fmul_rn(p1, ab.y)),
                                    __fmul_rn(p2, ab.z));
        const float nsh = __fsub_rn(ab.w, dot);         // == -s[h] bitwise
        const float w0 = __fmul_rn(nsh, ab.x);
        const float w1 = __fmul_rn(nsh, ab.y);
        const float w2 = __fmul_rn(nsh, ab.z);

        float m0 = -INFINITY, m1 = -INFINITY;
        #pragma unroll
        for (int j = 0; j < H; j += 2) {                // 13 pairs
            const float ta = __builtin_fmaf(w0, ax[j],
                             __builtin_fmaf(w1, ay[j],
                             __builtin_fmaf(w2, az[j], s[j])));
            const float tb = __builtin_fmaf(w0, ax[j + 1],
                             __builtin_fmaf(w1, ay[j + 1],
                             __builtin_fmaf(w2, az[j + 1], s[j + 1])));
            if (j & 2) m1 = max3f(ta, tb, m1); else m0 = max3f(ta, tb, m0);
        }
        const bool onz = (fmaxf(m0, m1) < EPSV);

        const float n2 = __builtin_fmaf(ab.x, ab.x,
                         __builtin_fmaf(ab.y, ab.y, __fmul_rn(ab.z, ab.z)));
        const float psq = __fmul_rn(__fmul_rn(nsh, nsh), n2);
        if (onz && psq < minpsq) { minpsq = psq; mini = h; }  // first argmin
    }
    const float minperp = __fsqrt_rn(minpsq);   // monotone: == min of sqrts

    // ---- edge pass: packed-uint argmin, pairs folded via v_min3_u32 ----
    unsigned umin = 0xFFFFFFFFu;
    #pragma unroll 2
    for (int v = 0; v < V; v += 2) {
        unsigned ua, ub;
        {
            const float4 V1 = sV1[v];
            const float4 E  = sE[v];
            const float dpe = __builtin_fmaf(p0, E.x,
                              __builtin_fmaf(p1, E.y, __fmul_rn(p2, E.z)));
            const float th = __builtin_fmaf(dpe, V1.w, E.w);
            const float ts = __builtin_amdgcn_fmed3f(th, 0.f, 1.f);
            const float g0 = __fsub_rn(p0, __builtin_fmaf(ts, E.x, V1.x));
            const float g1 = __fsub_rn(p1, __builtin_fmaf(ts, E.y, V1.y));
            const float g2 = __fsub_rn(p2, __builtin_fmaf(ts, E.z, V1.z));
            const float esq = __builtin_fmaf(g0, g0,
                              __builtin_fmaf(g1, g1, __fmul_rn(g2, g2)));
            ua = (__float_as_uint(esq) & ~63u) | (unsigned)v;
        }
        {
            const float4 V1 = sV1[v + 1];
            const float4 E  = sE[v + 1];
            const float dpe = __builtin_fmaf(p0, E.x,
                              __builtin_fmaf(p1, E.y, __fmul_rn(p2, E.z)));
            const float th = __builtin_fmaf(dpe, V1.w, E.w);
            const float ts = __builtin_amdgcn_fmed3f(th, 0.f, 1.f);
            const float g0 = __fsub_rn(p0, __builtin_fmaf(ts, E.x, V1.x));
            const float g1 = __fsub_rn(p1, __builtin_fmaf(ts, E.y, V1.y));
            const float g2 = __fsub_rn(p2, __builtin_fmaf(ts, E.z, V1.z));
            const float esq = __builtin_fmaf(g0, g0,
                              __builtin_fmaf(g1, g1, __fmul_rn(g2, g2)));
            ub = (__float_as_uint(esq) & ~63u) | (unsigned)(v + 1);
        }
        umin = min3u(ua, ub, umin);
    }
    const int midx = (int)(umin & 63u);

    // Winner recompute (same ops/inputs as in-loop -> bitwise identical).
    const float4 V1w = sV1[midx];
    const float4 Ew  = sE[midx];
    const float dpew = __builtin_fmaf(p0, Ew.x,
                       __builtin_fmaf(p1, Ew.y, __fmul_rn(p2, Ew.z)));
    const float thw = __builtin_fmaf(dpew, V1w.w, Ew.w);
    const float tsw = __builtin_amdgcn_fmed3f(thw, 0.f, 1.f);
    const float vm0 = __builtin_fmaf(tsw, Ew.x, V1w.x);
    const float vm1 = __builtin_fmaf(tsw, Ew.y, V1w.y);
    const float vm2 = __builtin_fmaf(tsw, Ew.z, V1w.z);
    const float w0 = __fsub_rn(p0, vm0);
    const float w1 = __fsub_rn(p1, vm1);
    const float w2 = __fsub_rn(p2, vm2);
    const float esqw = __builtin_fmaf(w0, w0,
                       __builtin_fmaf(w1, w1, __fmul_rn(w2, w2)));
    const float mine = __fsqrt_rn(esqw);        // == min_v sqrt(esq_v) bitwise

    // ---- select ----
    const int   fidx = is_neg ? maxi : mini;
    const float4 ga  = sAb[fidx];
    float dist = is_neg ? maxv : minperp;
    float g0 = ga.x, g1 = ga.y, g2 = ga.z;
    if (!is_neg && (mine < dist)) {
        dist = mine;
        g0 = __fdiv_rn(w0, mine);
        g1 = __fdiv_rn(w1, mine);
        g2 = __fdiv_rn(w2, mine);
    }

    const int idx = p * O + o;
    dist_out[idx] = dist;
    grad_out[idx * 3 + 0] = g0;
    grad_out[idx * 3 + 1] = g1;
    grad_out[idx * 3 + 2] = g2;
}

extern "C" void kernel_launch(void* const* d_in, const int* in_sizes, int n_in,
                              void* d_out, int out_size, void* d_ws, size_t ws_size,
                              hipStream_t stream) {
    const float* point = (const float*)d_in[0];
    const float* hA    = (const float*)d_in[1];
    const float* hb    = (const float*)d_in[2];
    const float* v1    = (const float*)d_in[3];
    const float* v2    = (const float*)d_in[4];
    float* out = (float*)d_out;

    dim3 grid(P / 256, O);
    zono_kernel<<<grid, dim3(256), 0, stream>>>(point, hA, hb, v1, v2,
                                                out, out + P * O);
}

// Round 16
// 17.708 us; speedup vs baseline: 1.1808x; 1.1808x over previous
//
#include <hip/hip_runtime.h>
#include <math.h>

namespace {
constexpr int P = 4096, O = 32, H = 26, V = 48;
constexpr int GPITCH = 28;            // Gram row stride (floats); 112B rows, 16B-aligned
constexpr float EPSV = 1e-4f;         // strict < EPSV == numpy's (f32 <= 1e-4 f64)
}

typedef float f32x2 __attribute__((ext_vector_type(2)));

// clang fuses fmaxf(fmaxf(a,b),c) -> v_max3_f32 (gfx9+)
__device__ __forceinline__ float max3f(float a, float b, float c) {
    return fmaxf(fmaxf(a, b), c);
}
// clang fuses to v_min3_u32
__device__ __forceinline__ unsigned min3u(unsigned a, unsigned b, unsigned c) {
    const unsigned ab = a < b ? a : b;
    return ab < c ? ab : c;
}

// One thread per (point p, object o).
// Gram trick: Appb[h][j] = s_j - s_h * G[h][j], G = A A^T in LDS.
// s_j keeps the reference's exact rounding (argmax/max_vals/is_neg exact).
// Face inner loop in PACKED f32 (f32x2 + __builtin_elementwise_fma/max ->
// v_pk_fma_f32 / v_pk_max_f32, VOP3P; per-element rounding == fmaf/fmaxf, so
// results are bit-identical). psq = nsh^2 * G[h][h]; one sqrt per pass
// (correctly-rounded sqrt is monotone).
// Edge pass: packed-uint argmin via v_min3_u32, winner recomputed (bitwise).
// Face loop ROLLED (R10: full unroll -> 256 VGPR + spill). No inline asm
// (R12: asm pk_fma = scheduling barrier + pair-building movs, regressed).
__global__ __launch_bounds__(256) void zono_kernel(
    const float* __restrict__ point,   // [P][3]
    const float* __restrict__ hA,      // [O][H][3]
    const float* __restrict__ hb,      // [O][H]
    const float* __restrict__ v1g,     // [O][V][3]
    const float* __restrict__ v2g,     // [O][V][3]
    float* __restrict__ dist_out,      // [P][O]
    float* __restrict__ grad_out)      // [P][O][3]
{
    __shared__ float4 sAb[H];            // {a0,a1,a2,b}
    __shared__ float  sG[H][GPITCH];     // Gram a_h . a_j
    __shared__ float4 sV1[V];            // {v1_0,v1_1,v1_2, inv_den}
    __shared__ float4 sE[V];             // {e0,e1,e2, -(v1.e)*inv_den}

    const int o   = blockIdx.y;
    const int tid = threadIdx.x;

    if (tid < H) {
        const float* a = hA + (o * H + tid) * 3;
        sAb[tid] = make_float4(a[0], a[1], a[2], hb[o * H + tid]);
    } else if (tid >= 32 && tid < 32 + V) {
        const int v = tid - 32;
        const float* A1 = v1g + (o * V + v) * 3;
        const float* A2 = v2g + (o * V + v) * 3;
        const float x0 = A1[0], x1 = A1[1], x2 = A1[2];
        const float e0 = __fsub_rn(A2[0], x0);
        const float e1 = __fsub_rn(A2[1], x1);
        const float e2 = __fsub_rn(A2[2], x2);
        const float den = __fadd_rn(__fadd_rn(__fmul_rn(e0, e0), __fmul_rn(e1, e1)),
                                    __fmul_rn(e2, e2));
        const float inv = __fdiv_rn(1.f, den);
        const float cv  = __fadd_rn(__fadd_rn(__fmul_rn(x0, e0), __fmul_rn(x1, e1)),
                                    __fmul_rn(x2, e2));
        const float nci = -__fmul_rn(cv, inv);
        sV1[v] = make_float4(x0, x1, x2, inv);
        sE[v]  = make_float4(e0, e1, e2, nci);
    }
    __syncthreads();

    // Build Gram table.
    for (int e = tid; e < H * H; e += 256) {
        const int h = e / H;
        const int j = e - h * H;
        const float4 A = sAb[h];
        const float4 B = sAb[j];
        sG[h][j] = __fadd_rn(__fadd_rn(__fmul_rn(A.x, B.x), __fmul_rn(A.y, B.y)),
                             __fmul_rn(A.z, B.z));
    }
    __syncthreads();

    const int p = blockIdx.x * blockDim.x + tid;
    const float p0 = point[p * 3 + 0];
    const float p1 = point[p * 3 + 1];
    const float p2 = point[p * 3 + 2];

    // ---- s_j (exact reference rounding) + argmax; packed into s2 pairs ----
    f32x2 s2[13];                        // compile-time indexed only
    float maxv = -INFINITY; int maxi = 0;
    #pragma unroll
    for (int j = 0; j < H; ++j) {
        const float4 ab = sAb[j];
        const float sj = __fsub_rn(
            __fadd_rn(__fadd_rn(__fmul_rn(p0, ab.x), __fmul_rn(p1, ab.y)),
                      __fmul_rn(p2, ab.z)),
            ab.w);
        s2[j >> 1][j & 1] = sj;
        if (sj > maxv) { maxv = sj; maxi = j; }        // first argmax
    }
    const bool is_neg = (maxv <= 0.f);

    // ---- face pass (ROLLED): t = pk_fma(nsh2, G-pair, s-pair) ----
    float minpsq = INFINITY; int mini = 0;
    for (int h = 0; h < H; ++h) {
        const float4 ab = sAb[h];                       // broadcast LDS read
        const float dot = __fadd_rn(__fadd_rn(__fmul_rn(p0, ab.x),
                                              __fmul_rn(p1, ab.y)),
                                    __fmul_rn(p2, ab.z));
        const float nsh = __fsub_rn(ab.w, dot);         // == -s[h] bitwise
        f32x2 nsh2; nsh2.x = nsh; nsh2.y = nsh;

        const f32x2* gRow2 = reinterpret_cast<const f32x2*>(&sG[h][0]);
        f32x2 M0; M0.x = -INFINITY; M0.y = -INFINITY;
        f32x2 M1 = M0;
        #pragma unroll
        for (int q = 0; q < 13; ++q) {
            const f32x2 t = __builtin_elementwise_fma(nsh2, gRow2[q], s2[q]);
            if (q & 1) M1 = __builtin_elementwise_max(M1, t);
            else       M0 = __builtin_elementwise_max(M0, t);
        }
        const f32x2 Mm = __builtin_elementwise_max(M0, M1);
        const bool onz = (fmaxf(Mm.x, Mm.y) < EPSV);

        const float psq = __fmul_rn(__fmul_rn(nsh, nsh), sG[h][h]);
        if (onz && psq < minpsq) { minpsq = psq; mini = h; }  // first argmin
    }
    const float minperp = __fsqrt_rn(minpsq);   // monotone: == min of sqrts

    // ---- edge pass: packed-uint argmin, pairs folded via v_min3_u32 ----
    unsigned umin = 0xFFFFFFFFu;
    #pragma unroll 2
    for (int v = 0; v < V; v += 2) {
        unsigned ua, ub;
        {
            const float4 V1 = sV1[v];
            const float4 E  = sE[v];
            const float dpe = __builtin_fmaf(p0, E.x,
                              __builtin_fmaf(p1, E.y, __fmul_rn(p2, E.z)));
            const float th = __builtin_fmaf(dpe, V1.w, E.w);
            const float ts = __builtin_amdgcn_fmed3f(th, 0.f, 1.f);
            const float g0 = __fsub_rn(p0, __builtin_fmaf(ts, E.x, V1.x));
            const float g1 = __fsub_rn(p1, __builtin_fmaf(ts, E.y, V1.y));
            const float g2 = __fsub_rn(p2, __builtin_fmaf(ts, E.z, V1.z));
            const float esq = __builtin_fmaf(g0, g0,
                              __builtin_fmaf(g1, g1, __fmul_rn(g2, g2)));
            ua = (__float_as_uint(esq) & ~63u) | (unsigned)v;
        }
        {
            const float4 V1 = sV1[v + 1];
            const float4 E  = sE[v + 1];
            const float dpe = __builtin_fmaf(p0, E.x,
                              __builtin_fmaf(p1, E.y, __fmul_rn(p2, E.z)));
            const float th = __builtin_fmaf(dpe, V1.w, E.w);
            const float ts = __builtin_amdgcn_fmed3f(th, 0.f, 1.f);
            const float g0 = __fsub_rn(p0, __builtin_fmaf(ts, E.x, V1.x));
            const float g1 = __fsub_rn(p1, __builtin_fmaf(ts, E.y, V1.y));
            const float g2 = __fsub_rn(p2, __builtin_fmaf(ts, E.z, V1.z));
            const float esq = __builtin_fmaf(g0, g0,
                              __builtin_fmaf(g1, g1, __fmul_rn(g2, g2)));
            ub = (__float_as_uint(esq) & ~63u) | (unsigned)(v + 1);
        }
        umin = min3u(ua, ub, umin);
    }
    const int midx = (int)(umin & 63u);

    // Winner recompute (same ops/inputs as in-loop -> bitwise identical).
    const float4 V1w = sV1[midx];
    const float4 Ew  = sE[midx];
    const float dpew = __builtin_fmaf(p0, Ew.x,
                       __builtin_fmaf(p1, Ew.y, __fmul_rn(p2, Ew.z)));
    const float thw = __builtin_fmaf(dpew, V1w.w, Ew.w);
    const float tsw = __builtin_amdgcn_fmed3f(thw, 0.f, 1.f);
    const float vm0 = __builtin_fmaf(tsw, Ew.x, V1w.x);
    const float vm1 = __builtin_fmaf(tsw, Ew.y, V1w.y);
    const float vm2 = __builtin_fmaf(tsw, Ew.z, V1w.z);
    const float w0 = __fsub_rn(p0, vm0);
    const float w1 = __fsub_rn(p1, vm1);
    const float w2 = __fsub_rn(p2, vm2);
    const float esqw = __builtin_fmaf(w0, w0,
                       __builtin_fmaf(w1, w1, __fmul_rn(w2, w2)));
    const float mine = __fsqrt_rn(esqw);        // == min_v sqrt(esq_v) bitwise

    // ---- select ----
    const int   fidx = is_neg ? maxi : mini;
    const float4 ga  = sAb[fidx];
    float dist = is_neg ? maxv : minperp;
    float g0 = ga.x, g1 = ga.y, g2 = ga.z;
    if (!is_neg && (mine < dist)) {
        dist = mine;
        g0 = __fdiv_rn(w0, mine);
        g1 = __fdiv_rn(w1, mine);
        g2 = __fdiv_rn(w2, mine);
    }

    const int idx = p * O + o;
    dist_out[idx] = dist;
    grad_out[idx * 3 + 0] = g0;
    grad_out[idx * 3 + 1] = g1;
    grad_out[idx * 3 + 2] = g2;
}

extern "C" void kernel_launch(void* const* d_in, const int* in_sizes, int n_in,
                              void* d_out, int out_size, void* d_ws, size_t ws_size,
                              hipStream_t stream) {
    const float* point = (const float*)d_in[0];
    const float* hA    = (const float*)d_in[1];
    const float* hb    = (const float*)d_in[2];
    const float* v1    = (const float*)d_in[3];
    const float* v2    = (const float*)d_in[4];
    float* out = (float*)d_out;

    dim3 grid(P / 256, O);
    zono_kernel<<<grid, dim3(256), 0, stream>>>(point, hA, hb, v1, v2,
                                                out, out + P * O);
}

// Round 17
// 16.849 us; speedup vs baseline: 1.2410x; 1.0510x over previous
//
#include <hip/hip_runtime.h>
#include <math.h>

namespace {
constexpr int P = 4096, O = 32, H = 26, V = 48;
constexpr int GPITCH = 28;            // Gram row stride (floats); 112B rows, 16B-aligned
constexpr float EPSV = 1e-4f;         // strict < EPSV == numpy's (f32 <= 1e-4 f64)
}

typedef float f32x2 __attribute__((ext_vector_type(2)));

// clang fuses to v_min3_u32
__device__ __forceinline__ unsigned min3u(unsigned a, unsigned b, unsigned c) {
    const unsigned ab = a < b ? a : b;
    return ab < c ? ab : c;
}

// One thread per (point p, object o).
// Gram trick: Appb[h][j] = s_j - s_h * G[h][j], G = A A^T in LDS.
// s_j keeps the reference's exact rounding (argmax/max_vals/is_neg exact).
// Face loop SOFTWARE-PIPELINED: h unrolled by 2 with A/B register buffers;
// row h+1's ds_reads issue before row h's compute, hiding LDS latency.
// Arithmetic identical to R16 (packed fma/max per-element == fmaf/fmaxf).
// psq = nsh^2 * G[h][h]; one sqrt per pass (monotone). Edge pass packed-uint
// argmin via v_min3_u32, winner recomputed (bitwise).
__global__ __launch_bounds__(256) void zono_kernel(
    const float* __restrict__ point,   // [P][3]
    const float* __restrict__ hA,      // [O][H][3]
    const float* __restrict__ hb,      // [O][H]
    const float* __restrict__ v1g,     // [O][V][3]
    const float* __restrict__ v2g,     // [O][V][3]
    float* __restrict__ dist_out,      // [P][O]
    float* __restrict__ grad_out)      // [P][O][3]
{
    __shared__ float4 sAb[H];            // {a0,a1,a2,b}
    __shared__ float  sG[H][GPITCH];     // Gram a_h . a_j
    __shared__ float4 sV1[V];            // {v1_0,v1_1,v1_2, inv_den}
    __shared__ float4 sE[V];             // {e0,e1,e2, -(v1.e)*inv_den}

    const int o   = blockIdx.y;
    const int tid = threadIdx.x;

    if (tid < H) {
        const float* a = hA + (o * H + tid) * 3;
        sAb[tid] = make_float4(a[0], a[1], a[2], hb[o * H + tid]);
    } else if (tid >= 32 && tid < 32 + V) {
        const int v = tid - 32;
        const float* A1 = v1g + (o * V + v) * 3;
        const float* A2 = v2g + (o * V + v) * 3;
        const float x0 = A1[0], x1 = A1[1], x2 = A1[2];
        const float e0 = __fsub_rn(A2[0], x0);
        const float e1 = __fsub_rn(A2[1], x1);
        const float e2 = __fsub_rn(A2[2], x2);
        const float den = __fadd_rn(__fadd_rn(__fmul_rn(e0, e0), __fmul_rn(e1, e1)),
                                    __fmul_rn(e2, e2));
        const float inv = __fdiv_rn(1.f, den);
        const float cv  = __fadd_rn(__fadd_rn(__fmul_rn(x0, e0), __fmul_rn(x1, e1)),
                                    __fmul_rn(x2, e2));
        const float nci = -__fmul_rn(cv, inv);
        sV1[v] = make_float4(x0, x1, x2, inv);
        sE[v]  = make_float4(e0, e1, e2, nci);
    }
    __syncthreads();

    // Build Gram table.
    for (int e = tid; e < H * H; e += 256) {
        const int h = e / H;
        const int j = e - h * H;
        const float4 A = sAb[h];
        const float4 B = sAb[j];
        sG[h][j] = __fadd_rn(__fadd_rn(__fmul_rn(A.x, B.x), __fmul_rn(A.y, B.y)),
                             __fmul_rn(A.z, B.z));
    }
    __syncthreads();

    const int p = blockIdx.x * blockDim.x + tid;
    const float p0 = point[p * 3 + 0];
    const float p1 = point[p * 3 + 1];
    const float p2 = point[p * 3 + 2];

    // ---- s_j (exact reference rounding) + argmax; packed into s2 pairs ----
    f32x2 s2[13];                        // compile-time indexed only
    float maxv = -INFINITY; int maxi = 0;
    #pragma unroll
    for (int j = 0; j < H; ++j) {
        const float4 ab = sAb[j];
        const float sj = __fsub_rn(
            __fadd_rn(__fadd_rn(__fmul_rn(p0, ab.x), __fmul_rn(p1, ab.y)),
                      __fmul_rn(p2, ab.z)),
            ab.w);
        s2[j >> 1][j & 1] = sj;
        if (sj > maxv) { maxv = sj; maxi = j; }        // first argmax
    }
    const bool is_neg = (maxv <= 0.f);

    // ---- face pass, pipelined: rows double-buffered in registers ----
    float minpsq = INFINITY; int mini = 0;
    {
        f32x2 RA[13], RB[13];
        float4 abA, abB;
        float dgA, dgB;
        // preload row 0
        #pragma unroll
        for (int q = 0; q < 13; ++q)
            RA[q] = reinterpret_cast<const f32x2*>(&sG[0][0])[q];
        abA = sAb[0];
        dgA = sG[0][0];

        for (int k = 0; k < 13; ++k) {
            const int ha = 2 * k, hbb = 2 * k + 1;

            // prefetch row hb (issues before row ha's compute consumes RA)
            #pragma unroll
            for (int q = 0; q < 13; ++q)
                RB[q] = reinterpret_cast<const f32x2*>(&sG[hbb][0])[q];
            abB = sAb[hbb];
            dgB = sG[hbb][hbb];

            // ---- compute row ha with RA ----
            {
                const float dot = __fadd_rn(__fadd_rn(__fmul_rn(p0, abA.x),
                                                      __fmul_rn(p1, abA.y)),
                                            __fmul_rn(p2, abA.z));
                const float nsh = __fsub_rn(abA.w, dot);    // == -s[ha] bitwise
                f32x2 nsh2; nsh2.x = nsh; nsh2.y = nsh;
                f32x2 M0; M0.x = -INFINITY; M0.y = -INFINITY;
                f32x2 M1 = M0;
                #pragma unroll
                for (int q = 0; q < 13; ++q) {
                    const f32x2 t = __builtin_elementwise_fma(nsh2, RA[q], s2[q]);
                    if (q & 1) M1 = __builtin_elementwise_max(M1, t);
                    else       M0 = __builtin_elementwise_max(M0, t);
                }
                const f32x2 Mm = __builtin_elementwise_max(M0, M1);
                const bool onz = (fmaxf(Mm.x, Mm.y) < EPSV);
                const float psq = __fmul_rn(__fmul_rn(nsh, nsh), dgA);
                if (onz && psq < minpsq) { minpsq = psq; mini = ha; }
            }

            // prefetch row ha+2 (issues before row hb's compute consumes RB)
            if (k < 12) {
                #pragma unroll
                for (int q = 0; q < 13; ++q)
                    RA[q] = reinterpret_cast<const f32x2*>(&sG[2 * k + 2][0])[q];
                abA = sAb[2 * k + 2];
                dgA = sG[2 * k + 2][2 * k + 2];
            }

            // ---- compute row hb with RB ----
            {
                const float dot = __fadd_rn(__fadd_rn(__fmul_rn(p0, abB.x),
                                                      __fmul_rn(p1, abB.y)),
                                            __fmul_rn(p2, abB.z));
                const float nsh = __fsub_rn(abB.w, dot);    // == -s[hb] bitwise
                f32x2 nsh2; nsh2.x = nsh; nsh2.y = nsh;
                f32x2 M0; M0.x = -INFINITY; M0.y = -INFINITY;
                f32x2 M1 = M0;
                #pragma unroll
                for (int q = 0; q < 13; ++q) {
                    const f32x2 t = __builtin_elementwise_fma(nsh2, RB[q], s2[q]);
                    if (q & 1) M1 = __builtin_elementwise_max(M1, t);
                    else       M0 = __builtin_elementwise_max(M0, t);
                }
                const f32x2 Mm = __builtin_elementwise_max(M0, M1);
                const bool onz = (fmaxf(Mm.x, Mm.y) < EPSV);
                const float psq = __fmul_rn(__fmul_rn(nsh, nsh), dgB);
                if (onz && psq < minpsq) { minpsq = psq; mini = hbb; }
            }
        }
    }
    const float minperp = __fsqrt_rn(minpsq);   // monotone: == min of sqrts

    // ---- edge pass: packed-uint argmin, pairs folded via v_min3_u32 ----
    unsigned umin = 0xFFFFFFFFu;
    #pragma unroll 2
    for (int v = 0; v < V; v += 2) {
        unsigned ua, ub;
        {
            const float4 V1 = sV1[v];
            const float4 E  = sE[v];
            const float dpe = __builtin_fmaf(p0, E.x,
                              __builtin_fmaf(p1, E.y, __fmul_rn(p2, E.z)));
            const float th = __builtin_fmaf(dpe, V1.w, E.w);
            const float ts = __builtin_amdgcn_fmed3f(th, 0.f, 1.f);
            const float g0 = __fsub_rn(p0, __builtin_fmaf(ts, E.x, V1.x));
            const float g1 = __fsub_rn(p1, __builtin_fmaf(ts, E.y, V1.y));
            const float g2 = __fsub_rn(p2, __builtin_fmaf(ts, E.z, V1.z));
            const float esq = __builtin_fmaf(g0, g0,
                              __builtin_fmaf(g1, g1, __fmul_rn(g2, g2)));
            ua = (__float_as_uint(esq) & ~63u) | (unsigned)v;
        }
        {
            const float4 V1 = sV1[v + 1];
            const float4 E  = sE[v + 1];
            const float dpe = __builtin_fmaf(p0, E.x,
                              __builtin_fmaf(p1, E.y, __fmul_rn(p2, E.z)));
            const float th = __builtin_fmaf(dpe, V1.w, E.w);
            const float ts = __builtin_amdgcn_fmed3f(th, 0.f, 1.f);
            const float g0 = __fsub_rn(p0, __builtin_fmaf(ts, E.x, V1.x));
            const float g1 = __fsub_rn(p1, __builtin_fmaf(ts, E.y, V1.y));
            const float g2 = __fsub_rn(p2, __builtin_fmaf(ts, E.z, V1.z));
            const float esq = __builtin_fmaf(g0, g0,
                              __builtin_fmaf(g1, g1, __fmul_rn(g2, g2)));
            ub = (__float_as_uint(esq) & ~63u) | (unsigned)(v + 1);
        }
        umin = min3u(ua, ub, umin);
    }
    const int midx = (int)(umin & 63u);

    // Winner recompute (same ops/inputs as in-loop -> bitwise identical).
    const float4 V1w = sV1[midx];
    const float4 Ew  = sE[midx];
    const float dpew = __builtin_fmaf(p0, Ew.x,
                       __builtin_fmaf(p1, Ew.y, __fmul_rn(p2, Ew.z)));
    const float thw = __builtin_fmaf(dpew, V1w.w, Ew.w);
    const float tsw = __builtin_amdgcn_fmed3f(thw, 0.f, 1.f);
    const float vm0 = __builtin_fmaf(tsw, Ew.x, V1w.x);
    const float vm1 = __builtin_fmaf(tsw, Ew.y, V1w.y);
    const float vm2 = __builtin_fmaf(tsw, Ew.z, V1w.z);
    const float w0 = __fsub_rn(p0, vm0);
    const float w1 = __fsub_rn(p1, vm1);
    const float w2 = __fsub_rn(p2, vm2);
    const float esqw = __builtin_fmaf(w0, w0,
                       __builtin_fmaf(w1, w1, __fmul_rn(w2, w2)));
    const float mine = __fsqrt_rn(esqw);        // == min_v sqrt(esq_v) bitwise

    // ---- select ----
    const int   fidx = is_neg ? maxi : mini;
    const float4 ga  = sAb[fidx];
    float dist = is_neg ? maxv : minperp;
    float g0 = ga.x, g1 = ga.y, g2 = ga.z;
    if (!is_neg && (mine < dist)) {
        dist = mine;
        g0 = __fdiv_rn(w0, mine);
        g1 = __fdiv_rn(w1, mine);
        g2 = __fdiv_rn(w2, mine);
    }

    const int idx = p * O + o;
    dist_out[idx] = dist;
    grad_out[idx * 3 + 0] = g0;
    grad_out[idx * 3 + 1] = g1;
    grad_out[idx * 3 + 2] = g2;
}

extern "C" void kernel_launch(void* const* d_in, const int* in_sizes, int n_in,
                              void* d_out, int out_size, void* d_ws, size_t ws_size,
                              hipStream_t stream) {
    const float* point = (const float*)d_in[0];
    const float* hA    = (const float*)d_in[1];
    const float* hb    = (const float*)d_in[2];
    const float* v1    = (const float*)d_in[3];
    const float* v2    = (const float*)d_in[4];
    float* out = (float*)d_out;

    dim3 grid(P / 256, O);
    zono_kernel<<<grid, dim3(256), 0, stream>>>(point, hA, hb, v1, v2,
                                                out, out + P * O);
}